// Round 8
// baseline (324.168 us; speedup 1.0000x reference)
//
#include <hip/hip_runtime.h>
#include <hip/hip_bf16.h>

typedef unsigned short u16;
using bf16_t = __hip_bfloat16;
typedef short short8 __attribute__((ext_vector_type(8)));
typedef float f32x4 __attribute__((ext_vector_type(4)));

__device__ __forceinline__ float b2f(u16 u) {
    return __uint_as_float((unsigned int)u << 16);
}
__device__ __forceinline__ u16 f2b(float f) {
    bf16_t h = __float2bfloat16(f);
    union { bf16_t h; u16 u; } cv; cv.h = h; return cv.u;
}
__device__ __forceinline__ float ldv(const void* p, size_t i, int f32) {
    return f32 ? ((const float*)p)[i] : b2f(((const u16*)p)[i]);
}
__device__ __forceinline__ uint4 pack8(float4 a, float4 b) {
    uint4 u;
    u.x = (unsigned)f2b(a.x) | ((unsigned)f2b(a.y) << 16);
    u.y = (unsigned)f2b(a.z) | ((unsigned)f2b(a.w) << 16);
    u.z = (unsigned)f2b(b.x) | ((unsigned)f2b(b.y) << 16);
    u.w = (unsigned)f2b(b.z) | ((unsigned)f2b(b.w) << 16);
    return u;
}
// XOR swizzle for stride-64(u16) LDS tiles: element (n,k) lives at
// n*64 + (k ^ ((n&7)<<3)). Involution in k for fixed n; 16B blocks preserved.
__device__ __forceinline__ int swz(int n, int k) {
    return k ^ ((n & 7) << 3);
}
// Async global->LDS DMA, 16B per lane. LDS dest must be wave-uniform base;
// HW writes lane i at base + i*16B. Global src is per-lane (pre-swizzled).
__device__ __forceinline__ void gl16(const u16* g, u16* l) {
    __builtin_amdgcn_global_load_lds(
        (const __attribute__((address_space(1))) unsigned int*)g,
        (__attribute__((address_space(3))) unsigned int*)l, 16, 0, 0);
}

// ---------------------------------------------------------------------------
// Input-dtype detector (flag=1 -> fp32 inputs & fp32 output).
// ---------------------------------------------------------------------------
__global__ void detect_kernel(const void* __restrict__ x, int* __restrict__ flag)
{
    const int t = threadIdx.x;
    const u16 h = ((const u16*)x)[2 * t];
    const int e = (h >> 7) & 0xFF;
    const int plaus = (e >= 112 && e <= 133) ? 1 : 0;
    const unsigned long long m = __ballot(plaus);
    if (t == 0) flag[0] = (__popcll(m) < 32) ? 1 : 0;
}

// x -> xb (bf16 always). 8 elements/thread.
__global__ __launch_bounds__(256)
void xcvt_kernel(const void* __restrict__ x, u16* __restrict__ xb,
                 const int* __restrict__ flagp)
{
    const size_t i = ((size_t)blockIdx.x * 256 + threadIdx.x) * 8;
    if (*flagp) {
        const float* xf = (const float*)x + i;
        const float4 f0 = *reinterpret_cast<const float4*>(xf);
        const float4 f1 = *reinterpret_cast<const float4*>(xf + 4);
        *reinterpret_cast<uint4*>(xb + i) = pack8(f0, f1);
    } else {
        *reinterpret_cast<uint4*>(xb + i) =
            *reinterpret_cast<const uint4*>((const u16*)x + i);
    }
}

// ---------------------------------------------------------------------------
// Merged preprocessing: blocks [0,1024): pe->peb; blocks [1024,1280):
// W->WT LDS-tiled transpose (Wq 64, Wkv 128, Wp 64 tiles).
// ---------------------------------------------------------------------------
__global__ __launch_bounds__(256)
void prep_kernel(const void* __restrict__ pe, u16* __restrict__ peb,
                 const void* __restrict__ Wq, u16* __restrict__ WqT,
                 const void* __restrict__ Wkv, u16* __restrict__ WkvT,
                 const void* __restrict__ Wp, u16* __restrict__ WpT,
                 const int* __restrict__ flagp)
{
    const int f32 = *flagp;
    __shared__ float tile[32][33];
    const int bid = blockIdx.x;
    if (bid < 1024) {
        const size_t i = ((size_t)bid * 256 + threadIdx.x) * 4;
        if (f32) {
            const float4 f = *reinterpret_cast<const float4*>((const float*)pe + i);
            ushort4 o; o.x = f2b(f.x); o.y = f2b(f.y); o.z = f2b(f.z); o.w = f2b(f.w);
            *reinterpret_cast<ushort4*>(peb + i) = o;
        } else {
            *reinterpret_cast<ushort4*>(peb + i) =
                *reinterpret_cast<const ushort4*>((const u16*)pe + i);
        }
        return;
    }
    int lb = bid - 1024;
    const void* W; u16* WT; int N;
    if (lb < 64)       { W = Wq;  WT = WqT;  N = 256; }
    else if (lb < 192) { W = Wkv; WT = WkvT; N = 512; lb -= 64; }
    else               { W = Wp;  WT = WpT;  N = 256; lb -= 192; }
    const int tx = threadIdx.x & 31, ty = threadIdx.x >> 5;   // ty 0..7
    const int bx = lb % (N >> 5);   // n tile
    const int by = lb / (N >> 5);   // k tile
    #pragma unroll
    for (int r = 0; r < 4; ++r) {
        const int k = by * 32 + ty + r * 8;
        const int n = bx * 32 + tx;
        tile[ty + r * 8][tx] = ldv(W, (size_t)k * N + n, f32);
    }
    __syncthreads();
    #pragma unroll
    for (int r = 0; r < 4; ++r) {
        const int n2 = bx * 32 + ty + r * 8;
        const int k2 = by * 32 + tx;
        WT[(size_t)n2 * 256 + k2] = f2b(tile[tx][ty + r * 8]);
    }
}

// ---------------------------------------------------------------------------
// MFMA GEMM v2, BN=256, BM=64 (grid 1024 -> 3-4 blocks/CU, was 512 -> 2).
// 4 waves 1(m)x4(n), wave tile 64x64 (acc[4][4]). BK=64.
// As[64][64] 8K + Bs[256][64] 32K, linear LDS, XOR-pre-swizzled DMA source.
// MODE 0: O0(bf16) = A@B                      (v-gemm)
// MODE 2: out = A@B + bias; fp32/bf16 store   (A = qy bf16)
// MODE 3: O0(bf16) = focus(A@B)               (q-gemm, focus fused)
// ---------------------------------------------------------------------------
template<int MODE>
__global__ __launch_bounds__(256, 2)
void gemm256(const void* __restrict__ Aany, const u16* __restrict__ Abf,
             const u16* __restrict__ BT, u16* __restrict__ O0,
             const void* __restrict__ extra, const int* __restrict__ flagp,
             int abf)
{
    const int f32 = *flagp;
    __shared__ u16 As[64 * 64];
    __shared__ u16 Bs[256 * 64];
    __shared__ float red2[4][64];
    __shared__ float red6[4][64];
    __shared__ float ratio_s[64];
    __shared__ float sscr[256];

    const int tid  = threadIdx.x;
    const int row0 = blockIdx.x * 64;
    const int lane = tid & 63;
    const int wv   = tid >> 6;
    const int wvu  = __builtin_amdgcn_readfirstlane(wv);
    const int wn   = wv * 64;                // wave col base
    const int l15  = lane & 15;
    const int lq   = lane >> 4;
    const int lr8  = lane >> 3;              // staging: row within 8-group
    const int lc8  = (lane & 7) * 8;         // staging: col (u16) within row

    if (MODE == 3) {
        const float p = ldv(extra, tid, f32);
        const float s = (p > 20.f) ? p : log1pf(expf(p));
        sscr[tid] = 1.0f / s;
    }

    f32x4 acc[4][4] = {};

    for (int k0 = 0; k0 < 256; k0 += 64) {
        // ---- B stage: wave w rows [w*64, w*64+64), 8 DMA instrs. ----------
        #pragma unroll
        for (int it = 0; it < 8; ++it) {
            const int r = wvu * 64 + it * 8 + lr8;
            gl16(BT + (size_t)r * 256 + k0 + swz(r, lc8),
                 &Bs[(wvu * 64 + it * 8) * 64]);
        }
        // ---- A stage: wave w rows [w*16, w*16+16), 2 DMA instrs. ----------
        if (MODE == 2 || abf || !f32) {
            const u16* Ab = (MODE == 2) ? Abf : (const u16*)Aany;
            #pragma unroll
            for (int it = 0; it < 2; ++it) {
                const int r = wvu * 16 + it * 8 + lr8;
                gl16(Ab + (size_t)(row0 + r) * 256 + k0 + swz(r, lc8),
                     &As[(wvu * 16 + it * 8) * 64]);
            }
        } else {
            const int ar = tid >> 2, ak = (tid & 3) * 16;
            const float* ag = (const float*)Aany +
                              (size_t)(row0 + ar) * 256 + k0 + ak;
            #pragma unroll
            for (int j = 0; j < 2; ++j) {
                const float4 f0 = *reinterpret_cast<const float4*>(ag + j * 8);
                const float4 f1 = *reinterpret_cast<const float4*>(ag + j * 8 + 4);
                *reinterpret_cast<uint4*>(
                    &As[ar * 64 + swz(ar, ak + j * 8)]) = pack8(f0, f1);
            }
        }
        __syncthreads();
        #pragma unroll
        for (int ks = 0; ks < 64; ks += 32) {
            const int ko = ks + lq * 8;
            short8 av[4], bv[4];
            #pragma unroll
            for (int i = 0; i < 4; ++i) {
                const int m = i * 16 + l15;
                av[i] = *reinterpret_cast<const short8*>(&As[m * 64 + swz(m, ko)]);
            }
            #pragma unroll
            for (int j = 0; j < 4; ++j) {
                const int n = wn + j * 16 + l15;
                bv[j] = *reinterpret_cast<const short8*>(&Bs[n * 64 + swz(n, ko)]);
            }
            #pragma unroll
            for (int i = 0; i < 4; ++i)
                #pragma unroll
                for (int j = 0; j < 4; ++j)
                    acc[i][j] = __builtin_amdgcn_mfma_f32_16x16x32_bf16(
                        av[i], bv[j], acc[i][j], 0, 0, 0);
        }
        __syncthreads();
    }

    if (MODE == 3) {
        // focus: xv=(relu+eps)/softplus; per-row s2/s6, 4-wave reduce.
        #pragma unroll
        for (int i = 0; i < 4; ++i) {
            #pragma unroll
            for (int rg = 0; rg < 4; ++rg) {
                const int lr = i * 16 + lq * 4 + rg;       // local row 0..63
                float s2 = 0.f, s6 = 0.f;
                #pragma unroll
                for (int j = 0; j < 4; ++j) {
                    const int col = wn + j * 16 + l15;
                    const float xv =
                        (fmaxf(acc[i][j][rg], 0.f) + 1e-6f) * sscr[col];
                    acc[i][j][rg] = xv;
                    const float x2 = xv * xv;
                    s2 += x2;
                    s6 += x2 * x2 * x2;
                }
                #pragma unroll
                for (int off = 1; off < 16; off <<= 1) {
                    s2 += __shfl_xor(s2, off);
                    s6 += __shfl_xor(s6, off);
                }
                if (l15 == 0) { red2[wv][lr] = s2; red6[wv][lr] = s6; }
            }
        }
        __syncthreads();
        if (tid < 64) {
            const float s2t = red2[0][tid] + red2[1][tid] + red2[2][tid] + red2[3][tid];
            const float s6t = red6[0][tid] + red6[1][tid] + red6[2][tid] + red6[3][tid];
            ratio_s[tid] = sqrtf(s2t / s6t);
        }
        __syncthreads();
    }

    // Store. C/D layout: row=(lane>>4)*4+reg, col=lane&15 (m89-verified).
    #pragma unroll
    for (int i = 0; i < 4; ++i) {
        #pragma unroll
        for (int j = 0; j < 4; ++j) {
            const int gcol = wn + j * 16 + l15;
            #pragma unroll
            for (int rg = 0; rg < 4; ++rg) {
                const int lr = i * 16 + lq * 4 + rg;
                const size_t oi = (size_t)(row0 + lr) * 256 + gcol;
                const float a = acc[i][j][rg];
                if (MODE == 0) {
                    O0[oi] = f2b(a);
                } else if (MODE == 3) {
                    O0[oi] = f2b(a * a * a * ratio_s[lr]);
                } else {
                    const float o = a + ldv(extra, gcol, f32);
                    if (f32) ((float*)O0)[oi] = o;
                    else     O0[oi] = f2b(o);
                }
            }
        }
    }
}

// ---------------------------------------------------------------------------
// Fused k-path v5: 64-row blocks, grid 1024 (fixes grid-bound occupancy:
// 2 -> 3+ blocks/CU). k = x @ Wkv[:,:256] + pe -> focus -> kvsum/ksum.
// GEMM: As[64][64] + Bs[256][64]. Phase 3: 2 passes, VsT[128][64]; pass p
// covers v-cols [128p,128p+128) = heads 4p..4p+3, wave w -> head 4p+w.
// Atomics once per block over 4 hash slots (contention per address as r7).
// LDS: GEMM 40K / phase23 {KsT 32K | VsT 16K} -> union 48K (+3.3K) -> 3/CU.
// ---------------------------------------------------------------------------
__global__ __launch_bounds__(256, 2)
void fusedk_kernel(const void* __restrict__ x, const u16* __restrict__ WkvT,
                   const u16* __restrict__ peb, const u16* __restrict__ v,
                   const void* __restrict__ sp,
                   float* __restrict__ kvsm, float* __restrict__ ksm,
                   const int* __restrict__ flagp, int abf)
{
    const int f32 = *flagp;
    __shared__ u16 smem[24576];          // 48 KB, phase-aliased
    __shared__ float red2[4][64];
    __shared__ float red6[4][64];
    __shared__ float ratio_s[64];
    __shared__ float sscr[256];
    u16* As  = smem;                     // [64][64]   (GEMM)
    u16* Bs  = smem + 4096;              // [256][64]  (GEMM)
    u16* KsT = smem;                     // [256][64]  (phase 2b/3)
    u16* VsT = smem + 16384;             // [128][64]  (phase 3, per pass)

    const int tid  = threadIdx.x;
    const int lane = tid & 63;
    const int wv   = tid >> 6;           // 0..3
    const int wvu  = __builtin_amdgcn_readfirstlane(wv);
    const int l15  = lane & 15;
    const int lq   = lane >> 4;
    const int wn   = wv * 64;
    const int lr8  = lane >> 3;
    const int lc8  = (lane & 7) * 8;

    {
        const float p = ldv(sp, tid, f32);
        const float s = (p > 20.f) ? p : log1pf(expf(p));
        sscr[tid] = 1.0f / s;
    }

    f32x4 cc[2][4] = {};                 // cc[p] = head 4p+wv
    float ksp[4] = {0.f, 0.f, 0.f, 0.f};

    const int b    = blockIdx.x >> 6;    // batch (64 rows/block)
    const int row0 = blockIdx.x * 64;
    const int nb   = row0 & 4095;

    // ---- Phase 1: GEMM (64x256, BK=64). -----------------------------------
    f32x4 acc[4][4] = {};
    for (int k0 = 0; k0 < 256; k0 += 64) {
        #pragma unroll
        for (int it = 0; it < 8; ++it) {
            const int r = wvu * 64 + it * 8 + lr8;
            gl16(WkvT + (size_t)r * 256 + k0 + swz(r, lc8),
                 &Bs[(wvu * 64 + it * 8) * 64]);
        }
        if (abf || !f32) {
            #pragma unroll
            for (int it = 0; it < 2; ++it) {
                const int r = wvu * 16 + it * 8 + lr8;
                gl16((const u16*)x + (size_t)(row0 + r) * 256 + k0 + swz(r, lc8),
                     &As[(wvu * 16 + it * 8) * 64]);
            }
        } else {
            const int ar = tid >> 2, ak = (tid & 3) * 16;
            const float* ag = (const float*)x +
                              (size_t)(row0 + ar) * 256 + k0 + ak;
            #pragma unroll
            for (int j = 0; j < 2; ++j) {
                const float4 f0 = *reinterpret_cast<const float4*>(ag + j * 8);
                const float4 f1 = *reinterpret_cast<const float4*>(ag + j * 8 + 4);
                *reinterpret_cast<uint4*>(
                    &As[ar * 64 + swz(ar, ak + j * 8)]) = pack8(f0, f1);
            }
        }
        __syncthreads();
        #pragma unroll
        for (int ks = 0; ks < 64; ks += 32) {
            const int ko = ks + lq * 8;
            short8 av[4], bvv[4];
            #pragma unroll
            for (int i = 0; i < 4; ++i) {
                const int m = i * 16 + l15;
                av[i] = *reinterpret_cast<const short8*>(&As[m * 64 + swz(m, ko)]);
            }
            #pragma unroll
            for (int j = 0; j < 4; ++j) {
                const int n = wn + j * 16 + l15;
                bvv[j] = *reinterpret_cast<const short8*>(&Bs[n * 64 + swz(n, ko)]);
            }
            #pragma unroll
            for (int i = 0; i < 4; ++i)
                #pragma unroll
                for (int j = 0; j < 4; ++j)
                    acc[i][j] = __builtin_amdgcn_mfma_f32_16x16x32_bf16(
                        av[i], bvv[j], acc[i][j], 0, 0, 0);
        }
        __syncthreads();
    }

    // ---- Phase 2a: +peb, normalize, s2/s6 reduce. -------------------------
    #pragma unroll
    for (int i = 0; i < 4; ++i) {
        #pragma unroll
        for (int rg = 0; rg < 4; ++rg) {
            const int lrow = i * 16 + lq * 4 + rg;
            float s2 = 0.f, s6 = 0.f;
            #pragma unroll
            for (int j = 0; j < 4; ++j) {
                const int col = wn + j * 16 + l15;
                const float t = acc[i][j][rg] +
                    b2f(peb[(size_t)(nb + lrow) * 256 + col]);
                const float xv = (fmaxf(t, 0.f) + 1e-6f) * sscr[col];
                acc[i][j][rg] = xv;
                const float x2 = xv * xv;
                s2 += x2;
                s6 += x2 * x2 * x2;
            }
            #pragma unroll
            for (int off = 1; off < 16; off <<= 1) {
                s2 += __shfl_xor(s2, off);
                s6 += __shfl_xor(s6, off);
            }
            if (l15 == 0) { red2[wv][lrow] = s2; red6[wv][lrow] = s6; }
        }
    }
    __syncthreads();
    if (tid < 64) {
        const float s2t = red2[0][tid] + red2[1][tid] + red2[2][tid] + red2[3][tid];
        const float s6t = red6[0][tid] + red6[1][tid] + red6[2][tid] + red6[3][tid];
        ratio_s[tid] = sqrtf(s2t / s6t);
    }
    __syncthreads();

    // ---- Phase 2b: finalize k -> KsT[d][r] (swz); ksum partials. ----------
    {
        float kscol[4] = {0.f, 0.f, 0.f, 0.f};
        #pragma unroll
        for (int i = 0; i < 4; ++i)
            #pragma unroll
            for (int rg = 0; rg < 4; ++rg) {
                const int lrow = i * 16 + lq * 4 + rg;
                const float rt = ratio_s[lrow];
                #pragma unroll
                for (int j = 0; j < 4; ++j) {
                    const float xv = acc[i][j][rg];
                    const float kf = xv * xv * xv * rt;
                    const int d = wn + j * 16 + l15;
                    KsT[d * 64 + swz(d, lrow)] = f2b(kf);
                    kscol[j] += kf;
                }
            }
        #pragma unroll
        for (int j = 0; j < 4; ++j) {
            float kp = kscol[j];
            kp += __shfl_xor(kp, 16);
            kp += __shfl_xor(kp, 32);
            ksp[j] = kp;
        }
    }

    // ---- Phase 3: two passes; pass p covers e in [128p, 128p+128). --------
    #pragma unroll
    for (int p = 0; p < 2; ++p) {
        // Stage VsT[e_local][r] (swz): thread row=lane, cols wv*32..+31.
        {
            const u16* vg = v + (size_t)(row0 + lane) * 256 + p * 128 + wv * 32;
            uint4 t0[4];
            #pragma unroll
            for (int j = 0; j < 4; ++j)
                t0[j] = *reinterpret_cast<const uint4*>(vg + j * 8);
            #pragma unroll
            for (int j = 0; j < 4; ++j) {
                const u16* pp = (const u16*)&t0[j];
                #pragma unroll
                for (int m = 0; m < 8; ++m) {
                    const int el = wv * 32 + j * 8 + m;   // 0..127
                    VsT[el * 64 + swz(el, lane)] = pp[m];
                }
            }
        }
        __syncthreads();
        // Wave wv computes head h = 4p + wv.
        {
            const int h  = p * 4 + wv;
            const int cb = h * 32;        // d-base in KsT
            const int el = wv * 32;       // e-local base in VsT
            #pragma unroll
            for (int kk = 0; kk < 64; kk += 32) {
                const int ko = kk + lq * 8;
                const short8 a0 = *reinterpret_cast<const short8*>(
                    &KsT[(cb + l15) * 64 + swz(cb + l15, ko)]);
                const short8 a1 = *reinterpret_cast<const short8*>(
                    &KsT[(cb + 16 + l15) * 64 + swz(cb + 16 + l15, ko)]);
                const short8 b0 = *reinterpret_cast<const short8*>(
                    &VsT[(el + l15) * 64 + swz(el + l15, ko)]);
                const short8 b1 = *reinterpret_cast<const short8*>(
                    &VsT[(el + 16 + l15) * 64 + swz(el + 16 + l15, ko)]);
                cc[p][0] = __builtin_amdgcn_mfma_f32_16x16x32_bf16(a0, b0, cc[p][0], 0, 0, 0);
                cc[p][1] = __builtin_amdgcn_mfma_f32_16x16x32_bf16(a0, b1, cc[p][1], 0, 0, 0);
                cc[p][2] = __builtin_amdgcn_mfma_f32_16x16x32_bf16(a1, b0, cc[p][2], 0, 0, 0);
                cc[p][3] = __builtin_amdgcn_mfma_f32_16x16x32_bf16(a1, b1, cc[p][3], 0, 0, 0);
            }
        }
        __syncthreads();
    }

    // ---- Atomics once per block (4-slot hash). ----------------------------
    const int slot = blockIdx.x & 3;
    float* ksb = ksm + (size_t)(slot * 16 + b) * 256;
    #pragma unroll
    for (int j = 0; j < 4; ++j)
        if (lane < 16)
            atomicAdd(&ksb[wn + j * 16 + lane], ksp[j]);
    #pragma unroll
    for (int hh = 0; hh < 2; ++hh) {
        const int h = hh * 4 + wv;       // cc[hh] holds head 4*hh+wv
        float* base = kvsm + ((size_t)(slot * 16 + b) * 8 + h) * 1024;
        #pragma unroll
        for (int rg = 0; rg < 4; ++rg) {
            const int d0 = lq * 4 + rg;
            atomicAdd(&base[(size_t)d0 * 32 + l15],             cc[hh][0][rg]);
            atomicAdd(&base[(size_t)d0 * 32 + 16 + l15],        cc[hh][1][rg]);
            atomicAdd(&base[(size_t)(d0 + 16) * 32 + l15],      cc[hh][2][rg]);
            atomicAdd(&base[(size_t)(d0 + 16) * 32 + 16 + l15], cc[hh][3][rg]);
        }
    }
}

// ---------------------------------------------------------------------------
// attn (MFMA) IN-PLACE on qy: out[t][h*32+e] = (q[t]·kvT[h][e]) / (zd+eps).
// Sums the 4 kvsum/ksum slots.
// ---------------------------------------------------------------------------
__global__ __launch_bounds__(256, 2)
void attn_mfma_kernel(u16* __restrict__ qy, const float* __restrict__ kvsum,
                      const float* __restrict__ ksum)
{
    __shared__ u16 qs[64 * 256];         // swizzled rows (32 KB)
    __shared__ u16 kvT[8 * 32 * 40];     // [h][e][d], stride 40 (20 KB)
    __shared__ float km[8][32];
    __shared__ float zds[64][8];
    const int tid  = threadIdx.x;
    const int lane = tid & 63;
    const int wv   = tid >> 6;
    const int wvu  = __builtin_amdgcn_readfirstlane(wv);
    const int l15  = lane & 15;
    const int lq   = lane >> 4;
    const int b    = blockIdx.x >> 6;        // 64 blocks per batch
    const int n0   = (blockIdx.x & 63) * 64; // row base within batch
    const float inv_n = 1.0f / 4096.0f;

    // ---- Stage q rows via DMA (src pre-swizzled per row). -----------------
    {
        const int qr2 = lane >> 5;           // row within 2-row DMA group
        const int qc8 = (lane & 31) * 8;     // col (u16)
        const u16* qb = qy + (size_t)(b * 4096 + n0) * 256;
        #pragma unroll
        for (int it = 0; it < 8; ++it) {
            const int r = wvu * 16 + it * 2 + qr2;
            gl16(qb + (size_t)r * 256 + (qc8 ^ ((r & 7) << 3)),
                 &qs[(wvu * 16 + it * 2) * 256]);
        }
    }
    // ---- kvT + km staging (sum 4 slots). ----------------------------------
    {
        const int h = tid >> 5, e = tid & 31;
        const float* kp = kvsum + (size_t)b * 8192 + h * 1024 + e;
        #pragma unroll
        for (int d = 0; d < 32; ++d) {
            const float s = kp[d * 32] +
                            kp[(size_t)16 * 8192 + d * 32] +
                            kp[(size_t)32 * 8192 + d * 32] +
                            kp[(size_t)48 * 8192 + d * 32];
            kvT[h * 1280 + e * 40 + d] = f2b(s * inv_n);
        }
        (&km[0][0])[tid] = (ksum[(size_t)b * 256 + tid] +
                            ksum[(size_t)(16 + b) * 256 + tid] +
                            ksum[(size_t)(32 + b) * 256 + tid] +
                            ksum[(size_t)(48 + b) * 256 + tid]) * inv_n;
    }
    __syncthreads();

    // ---- zd: once per (row, head); wave w handles heads 2w, 2w+1. ---------
    {
        const int zt = tid & 63;
        const int zh0 = (tid >> 6) * 2;
        #pragma unroll
        for (int hh = 0; hh < 2; ++hh) {
            const int h = zh0 + hh;
            float s = 0.f;
            #pragma unroll
            for (int d = 0; d < 32; ++d) {
                const int col = (h * 32 + d) ^ ((zt & 7) << 3);
                s = fmaf(b2f(qs[zt * 256 + col]), km[h][d], s);
            }
            zds[zt][h] = s;
        }
    }

    // ---- MFMA: wave rows [wvu*16, wvu*16+16), all 8 heads x 2 e-halves. ---
    f32x4 acc[8][2];
    #pragma unroll
    for (int h = 0; h < 8; ++h) {
        const int m = wvu * 16 + l15;
        const int col = (h * 32 + lq * 8) ^ ((m & 7) << 3);
        const short8 av = *reinterpret_cast<const short8*>(&qs[m * 256 + col]);
        const short8 b0 = *reinterpret_cast<const short8*>(
            &kvT[h * 1280 + l15 * 40 + lq * 8]);
        const short8 b1 = *reinterpret_cast<const short8*>(
            &kvT[h * 1280 + (16 + l15) * 40 + lq * 8]);
        const f32x4 z = {0.f, 0.f, 0.f, 0.f};
        acc[h][0] = __builtin_amdgcn_mfma_f32_16x16x32_bf16(av, b0, z, 0, 0, 0);
        acc[h][1] = __builtin_amdgcn_mfma_f32_16x16x32_bf16(av, b1, z, 0, 0, 0);
    }
    __syncthreads();

    // ---- Epilogue: divide by zd (broadcast read) and store. ---------------
    u16* qb = qy + (size_t)(b * 4096 + n0) * 256;
    #pragma unroll
    for (int h = 0; h < 8; ++h) {
        #pragma unroll
        for (int eh = 0; eh < 2; ++eh) {
            const int gcol = h * 32 + eh * 16 + l15;
            #pragma unroll
            for (int rg = 0; rg < 4; ++rg) {
                const int lr = wvu * 16 + lq * 4 + rg;
                const float z = 1.0f / (zds[lr][h] + 1e-6f);
                qb[(size_t)lr * 256 + gcol] = f2b(acc[h][eh][rg] * z);
            }
        }
    }
}

// ---------------------------------------------------------------------------
// Depthwise 5x5 conv: LDS-staged 12x12x256 halo tile, thread=channel,
// register sliding 5x12 window, 8x8 outputs/thread, += into y with bias.
// ---------------------------------------------------------------------------
__global__ __launch_bounds__(256, 2)
void conv_add_kernel(const u16* __restrict__ v, const void* __restrict__ w,
                     const void* __restrict__ bias, u16* __restrict__ y,
                     const int* __restrict__ flagp)
{
    const int f32 = *flagp;
    __shared__ u16 vt[144 * 256];   // [py*12+px][ch], 73728 B
    __shared__ float wl[800];
    __shared__ float bl[32];
    const int tid = threadIdx.x;
    for (int i = tid; i < 800; i += 256) wl[i] = ldv(w, i, f32);
    if (tid < 32) bl[tid] = ldv(bias, tid, f32);

    const int bb = blockIdx.x >> 6;
    const int ty = (blockIdx.x >> 3) & 7;
    const int tx = blockIdx.x & 7;
    const int y0 = ty * 8, x0 = tx * 8;
    const u16* vb = v + (size_t)bb * 4096 * 256;

    #pragma unroll
    for (int it = 0; it < 18; ++it) {
        const int idx = it * 256 + tid;       // 0..4607
        const int px  = idx >> 5;             // 0..143
        const int c8  = (idx & 31) * 8;
        const int py  = px / 12, pxx = px - py * 12;
        const int yy = y0 + py - 2, xx = x0 + pxx - 2;
        uint4 val = {0u, 0u, 0u, 0u};
        if (yy >= 0 && yy < 64 && xx >= 0 && xx < 64)
            val = *reinterpret_cast<const uint4*>(
                vb + (size_t)((yy << 6) + xx) * 256 + c8);
        *reinterpret_cast<uint4*>(&vt[px * 256 + c8]) = val;
    }
    __syncthreads();

    const int c  = tid;            // channel
    const int dc = c & 31;
    float wreg[25];
    #pragma unroll
    for (int i = 0; i < 25; ++i) wreg[i] = wl[dc * 25 + i];
    const float bv = bl[dc];

    float win[5][12];
    #pragma unroll
    for (int r = 0; r < 5; ++r)
        #pragma unroll
        for (int cc = 0; cc < 12; ++cc)
            win[r][cc] = b2f(vt[(r * 12 + cc) * 256 + c]);

    u16* yb = y + ((size_t)bb * 4096 + (size_t)y0 * 64 + x0) * 256 + c;
    #pragma unroll
    for (int oy = 0; oy < 8; ++oy) {
        if (oy) {
            #pragma unroll
            for (int r = 0; r < 4; ++r)
                #pragma unroll
                for (int cc = 0; cc < 12; ++cc) win[r][cc] = win[r + 1][cc];
            #pragma unroll
            for (int cc = 0; cc < 12; ++cc)
                win[4][cc] = b2f(vt[((oy + 4) * 12 + cc) * 256 + c]);
        }
        #pragma unroll
        for (int ox = 0; ox < 8; ++ox) {
            float s = 0.f;
            #pragma unroll
            for (int ky = 0; ky < 5; ++ky)
                #pragma unroll
                for (int kx = 0; kx < 5; ++kx)
                    s = fmaf(win[ky][ox + kx], wreg[ky * 5 + kx], s);
            u16* yp = yb + (size_t)(oy * 64 + ox) * 256;
            *yp = f2b(b2f(*yp) + s + bv);
        }
    }
}

// ---------------------------------------------------------------------------
extern "C" void kernel_launch(void* const* d_in, const int* in_sizes, int n_in,
                              void* d_out, int out_size, void* d_ws, size_t ws_size,
                              hipStream_t stream)
{
    (void)in_sizes; (void)n_in; (void)out_size;
    const void* x   = d_in[0];
    const void* Wq  = d_in[1];
    const void* Wkv = d_in[2];
    const void* Wp  = d_in[3];
    const void* bp  = d_in[4];
    const void* sp  = d_in[5];
    const void* pe  = d_in[6];
    const void* dw  = d_in[7];
    const void* db  = d_in[8];

    // ws layout:
    // [flag 64B][kvsm 2M (4 slots)][ksm 64K (4 slots)][WqT 128K][WkvT 256K]
    // [WpT 128K][peb 2M][qy 32M][xb 32M (only if ws large enough)]
    int*   flag = (int*)d_ws;
    float* kvsm = (float*)((char*)d_ws + 64);
    float* ksm  = kvsm + 524288;
    u16*   WqT  = (u16*)(ksm + 16384);
    u16*   WkvT = WqT + 65536;
    u16*   WpT  = WkvT + 131072;
    u16*   peb  = WpT + 65536;
    u16*   qy   = peb + 1048576;
    u16*   xb   = qy + (size_t)16777216;
    // v (bf16, 33.5 MB) parked at the START of d_out (dead before the final
    // GEMM overwrites d_out).
    u16*   v    = (u16*)d_out;

    const size_t need = (size_t)((char*)(xb + 16777216) - (char*)d_ws);
    const int big = (ws_size >= need) ? 1 : 0;

    hipMemsetAsync(kvsm, 0, (524288 + 16384) * sizeof(float), stream);
    detect_kernel<<<1, 64, 0, stream>>>(x, flag);
    if (big) xcvt_kernel<<<8192, 256, 0, stream>>>(x, xb, flag);
    prep_kernel<<<1280, 256, 0, stream>>>(pe, peb, Wq, WqT, Wkv, WkvT,
                                          Wp, WpT, flag);

    const void* Ax = big ? (const void*)xb : x;

    // q = focus(x @ Wq)
    hipLaunchKernelGGL((gemm256<3>), dim3(1024), dim3(256), 0, stream,
                       Ax, (const u16*)nullptr, WqT, qy, sp, flag, big);
    // v = x @ Wkv[:, 256:]
    hipLaunchKernelGGL((gemm256<0>), dim3(1024), dim3(256), 0, stream,
                       Ax, (const u16*)nullptr, WkvT + (size_t)256 * 256, v,
                       (const void*)nullptr, flag, big);
    // fused k path: gemm + pe + focus + kvsum/ksum (k never materialized)
    fusedk_kernel<<<1024, 256, 0, stream>>>(Ax, WkvT, peb, v, sp, kvsm, ksm,
                                            flag, big);

    attn_mfma_kernel<<<1024, 256, 0, stream>>>(qy, kvsm, ksm);
    conv_add_kernel<<<1024, 256, 0, stream>>>(v, dw, db, qy, flag);
    hipLaunchKernelGGL((gemm256<2>), dim3(1024), dim3(256), 0, stream,
                       (const void*)nullptr, qy, WpT, (u16*)d_out, bp, flag, 0);
}

// Round 9
// 308.486 us; speedup vs baseline: 1.0508x; 1.0508x over previous
//
#include <hip/hip_runtime.h>
#include <hip/hip_bf16.h>

typedef unsigned short u16;
using bf16_t = __hip_bfloat16;
typedef short short8 __attribute__((ext_vector_type(8)));
typedef float f32x4 __attribute__((ext_vector_type(4)));

__device__ __forceinline__ float b2f(u16 u) {
    return __uint_as_float((unsigned int)u << 16);
}
__device__ __forceinline__ u16 f2b(float f) {
    bf16_t h = __float2bfloat16(f);
    union { bf16_t h; u16 u; } cv; cv.h = h; return cv.u;
}
__device__ __forceinline__ float ldv(const void* p, size_t i, int f32) {
    return f32 ? ((const float*)p)[i] : b2f(((const u16*)p)[i]);
}
__device__ __forceinline__ uint4 pack8(float4 a, float4 b) {
    uint4 u;
    u.x = (unsigned)f2b(a.x) | ((unsigned)f2b(a.y) << 16);
    u.y = (unsigned)f2b(a.z) | ((unsigned)f2b(a.w) << 16);
    u.z = (unsigned)f2b(b.x) | ((unsigned)f2b(b.y) << 16);
    u.w = (unsigned)f2b(b.z) | ((unsigned)f2b(b.w) << 16);
    return u;
}
// XOR swizzle for stride-64(u16) = 128B LDS rows (KsT/VsT/attn tiles).
__device__ __forceinline__ int swz(int n, int k) {
    return k ^ ((n & 7) << 3);
}
// XOR swizzle for stride-32(u16) = 64B LDS rows (BK=32 GEMM tiles):
// cell (n, blk) holds element (n, blk^(n&3)); blocks are 8 u16 = 16B.
__device__ __forceinline__ int swz32(int n, int kblk) {
    return (kblk ^ (n & 3)) << 3;
}
// Async global->LDS DMA, 16B per lane. LDS dest wave-uniform base; HW
// writes lane i at base + i*16B. Global src per-lane (pre-swizzled).
__device__ __forceinline__ void gl16(const u16* g, u16* l) {
    __builtin_amdgcn_global_load_lds(
        (const __attribute__((address_space(1))) unsigned int*)g,
        (__attribute__((address_space(3))) unsigned int*)l, 16, 0, 0);
}

// ---------------------------------------------------------------------------
// Input-dtype detector (flag=1 -> fp32 inputs & fp32 output).
// ---------------------------------------------------------------------------
__global__ void detect_kernel(const void* __restrict__ x, int* __restrict__ flag)
{
    const int t = threadIdx.x;
    const u16 h = ((const u16*)x)[2 * t];
    const int e = (h >> 7) & 0xFF;
    const int plaus = (e >= 112 && e <= 133) ? 1 : 0;
    const unsigned long long m = __ballot(plaus);
    if (t == 0) flag[0] = (__popcll(m) < 32) ? 1 : 0;
}

// x -> xb (bf16 always). 8 elements/thread.
__global__ __launch_bounds__(256)
void xcvt_kernel(const void* __restrict__ x, u16* __restrict__ xb,
                 const int* __restrict__ flagp)
{
    const size_t i = ((size_t)blockIdx.x * 256 + threadIdx.x) * 8;
    if (*flagp) {
        const float* xf = (const float*)x + i;
        const float4 f0 = *reinterpret_cast<const float4*>(xf);
        const float4 f1 = *reinterpret_cast<const float4*>(xf + 4);
        *reinterpret_cast<uint4*>(xb + i) = pack8(f0, f1);
    } else {
        *reinterpret_cast<uint4*>(xb + i) =
            *reinterpret_cast<const uint4*>((const u16*)x + i);
    }
}

// ---------------------------------------------------------------------------
// Merged preprocessing: blocks [0,1024): pe->peb; blocks [1024,1280):
// W->WT LDS-tiled transpose (Wq 64, Wkv 128, Wp 64 tiles).
// ---------------------------------------------------------------------------
__global__ __launch_bounds__(256)
void prep_kernel(const void* __restrict__ pe, u16* __restrict__ peb,
                 const void* __restrict__ Wq, u16* __restrict__ WqT,
                 const void* __restrict__ Wkv, u16* __restrict__ WkvT,
                 const void* __restrict__ Wp, u16* __restrict__ WpT,
                 const int* __restrict__ flagp)
{
    const int f32 = *flagp;
    __shared__ float tile[32][33];
    const int bid = blockIdx.x;
    if (bid < 1024) {
        const size_t i = ((size_t)bid * 256 + threadIdx.x) * 4;
        if (f32) {
            const float4 f = *reinterpret_cast<const float4*>((const float*)pe + i);
            ushort4 o; o.x = f2b(f.x); o.y = f2b(f.y); o.z = f2b(f.z); o.w = f2b(f.w);
            *reinterpret_cast<ushort4*>(peb + i) = o;
        } else {
            *reinterpret_cast<ushort4*>(peb + i) =
                *reinterpret_cast<const ushort4*>((const u16*)pe + i);
        }
        return;
    }
    int lb = bid - 1024;
    const void* W; u16* WT; int N;
    if (lb < 64)       { W = Wq;  WT = WqT;  N = 256; }
    else if (lb < 192) { W = Wkv; WT = WkvT; N = 512; lb -= 64; }
    else               { W = Wp;  WT = WpT;  N = 256; lb -= 192; }
    const int tx = threadIdx.x & 31, ty = threadIdx.x >> 5;   // ty 0..7
    const int bx = lb % (N >> 5);   // n tile
    const int by = lb / (N >> 5);   // k tile
    #pragma unroll
    for (int r = 0; r < 4; ++r) {
        const int k = by * 32 + ty + r * 8;
        const int n = bx * 32 + tx;
        tile[ty + r * 8][tx] = ldv(W, (size_t)k * N + n, f32);
    }
    __syncthreads();
    #pragma unroll
    for (int r = 0; r < 4; ++r) {
        const int n2 = bx * 32 + ty + r * 8;
        const int k2 = by * 32 + tx;
        WT[(size_t)n2 * 256 + k2] = f2b(tile[tx][ty + r * 8]);
    }
}

// ---------------------------------------------------------------------------
// MFMA GEMM v3, BN=256, BM=128 (r7 geometry), BK=32 DOUBLE-BUFFERED 2-phase:
// issue STAGE(t+1) into buf^1 BEFORE computing buf t -> DMA latency hides
// under the 32 MFMA of the current step (T3-min recipe). LDS 2x24K = 48K.
// 4 waves 2(m)x2(n), wave tile 64x128 (acc[4][8]).
// MODE 0: O0(bf16) = A@B                      (v-gemm)
// MODE 2: out = A@B + bias; fp32/bf16 store   (A = qy bf16)
// MODE 3: O0(bf16) = focus(A@B)               (q-gemm, focus fused)
// ---------------------------------------------------------------------------
template<int MODE>
__global__ __launch_bounds__(256, 2)
void gemm256(const void* __restrict__ Aany, const u16* __restrict__ Abf,
             const u16* __restrict__ BT, u16* __restrict__ O0,
             const void* __restrict__ extra, const int* __restrict__ flagp,
             int abf)
{
    const int f32 = *flagp;
    __shared__ u16 smem[24576];      // 2 x { As[128][32] 4096 | Bs[256][32] 8192 }
    __shared__ float red2[2][128];
    __shared__ float red6[2][128];
    __shared__ float ratio_s[128];
    __shared__ float sscr[256];

    const int tid  = threadIdx.x;
    const int row0 = blockIdx.x * 128;
    const int lane = tid & 63;
    const int wv   = tid >> 6;
    const int wvu  = __builtin_amdgcn_readfirstlane(wv);
    const int wm   = (wv & 1) * 64;          // wave row base
    const int wn   = (wv >> 1) * 128;        // wave col base
    const int l15  = lane & 15;
    const int lq   = lane >> 4;
    const int lr4  = lane >> 2;              // staging: row within 16-group
    const int lb3  = lane & 3;               // staging: 16B col-block

    if (MODE == 3) {
        const float p = ldv(extra, tid, f32);
        const float s = (p > 20.f) ? p : log1pf(expf(p));
        sscr[tid] = 1.0f / s;
    }

    const int use_dma_a = (MODE == 2) || abf || !f32;
    const u16* Ab = (MODE == 2) ? Abf : (const u16*)Aany;

    // ---- stage K-step t (k0 = t*32) into buffer buf. ----------------------
    auto stage = [&](int k0, int buf) {
        u16* As = smem + buf * 12288;
        u16* Bs = As + 4096;
        #pragma unroll
        for (int d = 0; d < 4; ++d) {          // B: wave rows [w*64, +64)
            const int r = wvu * 64 + d * 16 + lr4;
            gl16(BT + (size_t)r * 256 + k0 + swz32(r, lb3),
                 &Bs[(wvu * 64 + d * 16) * 32]);
        }
        if (use_dma_a) {
            #pragma unroll
            for (int d = 0; d < 2; ++d) {      // A: wave rows [w*32, +32)
                const int r = wvu * 32 + d * 16 + lr4;
                gl16(Ab + (size_t)(row0 + r) * 256 + k0 + swz32(r, lb3),
                     &As[(wvu * 32 + d * 16) * 32]);
            }
        } else {
            const int sr = tid >> 1, skb = (tid & 1) * 2;  // 2 col-blocks
            const float* ag = (const float*)Aany +
                              (size_t)(row0 + sr) * 256 + k0 + skb * 8;
            #pragma unroll
            for (int j = 0; j < 2; ++j) {
                const float4 f0 = *reinterpret_cast<const float4*>(ag + j * 8);
                const float4 f1 = *reinterpret_cast<const float4*>(ag + j * 8 + 4);
                *reinterpret_cast<uint4*>(
                    &As[sr * 32 + swz32(sr, skb + j)]) = pack8(f0, f1);
            }
        }
    };

    f32x4 acc[4][8] = {};

    stage(0, 0);
    __syncthreads();
    for (int t = 0; t < 8; ++t) {
        if (t < 7) stage((t + 1) * 32, (t + 1) & 1);
        const u16* As = smem + (t & 1) * 12288;
        const u16* Bs = As + 4096;
        short8 av[4], bv[8];
        #pragma unroll
        for (int i = 0; i < 4; ++i) {
            const int m = wm + i * 16 + l15;
            av[i] = *reinterpret_cast<const short8*>(&As[m * 32 + swz32(m, lq)]);
        }
        #pragma unroll
        for (int j = 0; j < 8; ++j) {
            const int n = wn + j * 16 + l15;
            bv[j] = *reinterpret_cast<const short8*>(&Bs[n * 32 + swz32(n, lq)]);
        }
        #pragma unroll
        for (int i = 0; i < 4; ++i)
            #pragma unroll
            for (int j = 0; j < 8; ++j)
                acc[i][j] = __builtin_amdgcn_mfma_f32_16x16x32_bf16(
                    av[i], bv[j], acc[i][j], 0, 0, 0);
        __syncthreads();
    }

    if (MODE == 3) {
        // focus: xv=(relu+eps)/softplus; per-row s2=sum xv^2, s6=sum xv^6.
        #pragma unroll
        for (int i = 0; i < 4; ++i) {
            #pragma unroll
            for (int rg = 0; rg < 4; ++rg) {
                const int lr = wm + i * 16 + lq * 4 + rg;   // local row 0..127
                float s2 = 0.f, s6 = 0.f;
                #pragma unroll
                for (int j = 0; j < 8; ++j) {
                    const int col = wn + j * 16 + l15;
                    const float xv =
                        (fmaxf(acc[i][j][rg], 0.f) + 1e-6f) * sscr[col];
                    acc[i][j][rg] = xv;
                    const float x2 = xv * xv;
                    s2 += x2;
                    s6 += x2 * x2 * x2;
                }
                #pragma unroll
                for (int off = 1; off < 16; off <<= 1) {
                    s2 += __shfl_xor(s2, off);
                    s6 += __shfl_xor(s6, off);
                }
                if (l15 == 0) { red2[wv >> 1][lr] = s2; red6[wv >> 1][lr] = s6; }
            }
        }
        __syncthreads();
        if (tid < 128)
            ratio_s[tid] = sqrtf((red2[0][tid] + red2[1][tid]) /
                                 (red6[0][tid] + red6[1][tid]));
        __syncthreads();
    }

    // Store. C/D layout: row=(lane>>4)*4+reg, col=lane&15 (m89-verified).
    #pragma unroll
    for (int i = 0; i < 4; ++i) {
        #pragma unroll
        for (int j = 0; j < 8; ++j) {
            const int gcol = wn + j * 16 + l15;
            #pragma unroll
            for (int rg = 0; rg < 4; ++rg) {
                const int lr = wm + i * 16 + lq * 4 + rg;
                const size_t oi = (size_t)(row0 + lr) * 256 + gcol;
                const float a = acc[i][j][rg];
                if (MODE == 0) {
                    O0[oi] = f2b(a);
                } else if (MODE == 3) {
                    O0[oi] = f2b(a * a * a * ratio_s[lr]);
                } else {
                    const float o = a + ldv(extra, gcol, f32);
                    if (f32) ((float*)O0)[oi] = o;
                    else     O0[oi] = f2b(o);
                }
            }
        }
    }
}

// ---------------------------------------------------------------------------
// Fused k-path v6: r7 geometry (128 rows/block, chunk-merged GEMM, grid 512,
// register kvsum accum, 2-slot atomics) with the GEMM phase restructured to
// BK=32 double-buffered 2-phase prefetch (same as gemm256 v3).
// Phase 3: 2 passes, VsT[128][64]; pass p covers e in [128p,128p+128),
// wave w -> head 4p+w. LDS: GEMM 48K / phase23 {KsT 32K | VsT 16K}.
// ---------------------------------------------------------------------------
__global__ __launch_bounds__(256, 2)
void fusedk_kernel(const void* __restrict__ x, const u16* __restrict__ WkvT,
                   const u16* __restrict__ peb, const u16* __restrict__ v,
                   const void* __restrict__ sp,
                   float* __restrict__ kvsm, float* __restrict__ ksm,
                   const int* __restrict__ flagp, int abf)
{
    const int f32 = *flagp;
    __shared__ u16 smem[24576];          // GEMM: 2 x {As 4096 | Bs 8192}
    __shared__ float red2[4][64];        // phase23: KsT 16384 | VsT 8192
    __shared__ float red6[4][64];
    __shared__ float ratio_s[64];
    __shared__ float sscr[256];
    u16* KsT = smem;                     // [256][64] swz
    u16* VsT = smem + 16384;             // [128][64] swz

    const int tid  = threadIdx.x;
    const int lane = tid & 63;
    const int wv   = tid >> 6;           // 0..3
    const int wvu  = __builtin_amdgcn_readfirstlane(wv);
    const int l15  = lane & 15;
    const int lq   = lane >> 4;
    const int wn   = wv * 64;
    const int lr4  = lane >> 2;
    const int lb3  = lane & 3;

    {
        const float p = ldv(sp, tid, f32);
        const float s = (p > 20.f) ? p : log1pf(expf(p));
        sscr[tid] = 1.0f / s;
    }

    f32x4 cc[2][4] = {};                 // cc[p] = head 4p+wv
    float ksp[4] = {0.f, 0.f, 0.f, 0.f};

    const int b    = blockIdx.x >> 5;    // batch (128 rows/block)
    const int row0 = blockIdx.x * 128;

    // ---- stage K-step (k0) into buffer buf. -------------------------------
    auto stage = [&](int k0, int buf) {
        u16* As = smem + buf * 12288;
        u16* Bs = As + 4096;
        #pragma unroll
        for (int d = 0; d < 4; ++d) {          // B: wave rows [w*64, +64)
            const int r = wvu * 64 + d * 16 + lr4;
            gl16(WkvT + (size_t)r * 256 + k0 + swz32(r, lb3),
                 &Bs[(wvu * 64 + d * 16) * 32]);
        }
        if (abf || !f32) {
            #pragma unroll
            for (int d = 0; d < 2; ++d) {      // A: wave rows [w*32, +32)
                const int r = wvu * 32 + d * 16 + lr4;
                gl16((const u16*)x + (size_t)(row0 + r) * 256 + k0 + swz32(r, lb3),
                     &As[(wvu * 32 + d * 16) * 32]);
            }
        } else {
            const int sr = tid >> 1, skb = (tid & 1) * 2;
            const float* ag = (const float*)x +
                              (size_t)(row0 + sr) * 256 + k0 + skb * 8;
            #pragma unroll
            for (int j = 0; j < 2; ++j) {
                const float4 f0 = *reinterpret_cast<const float4*>(ag + j * 8);
                const float4 f1 = *reinterpret_cast<const float4*>(ag + j * 8 + 4);
                *reinterpret_cast<uint4*>(
                    &As[sr * 32 + swz32(sr, skb + j)]) = pack8(f0, f1);
            }
        }
    };

    // ---- Phase 1: GEMM, both 64-row chunks, 2-phase BK=32 dbuf. -----------
    f32x4 acc[2][4][4] = {};
    stage(0, 0);
    __syncthreads();
    for (int t = 0; t < 8; ++t) {
        if (t < 7) stage((t + 1) * 32, (t + 1) & 1);
        const u16* As = smem + (t & 1) * 12288;
        const u16* Bs = As + 4096;
        short8 bvv[4];
        #pragma unroll
        for (int j = 0; j < 4; ++j) {
            const int n = wn + j * 16 + l15;
            bvv[j] = *reinterpret_cast<const short8*>(&Bs[n * 32 + swz32(n, lq)]);
        }
        #pragma unroll
        for (int c = 0; c < 2; ++c) {
            short8 av[4];
            #pragma unroll
            for (int i = 0; i < 4; ++i) {
                const int m = c * 64 + i * 16 + l15;
                av[i] = *reinterpret_cast<const short8*>(&As[m * 32 + swz32(m, lq)]);
            }
            #pragma unroll
            for (int i = 0; i < 4; ++i)
                #pragma unroll
                for (int j = 0; j < 4; ++j)
                    acc[c][i][j] = __builtin_amdgcn_mfma_f32_16x16x32_bf16(
                        av[i], bvv[j], acc[c][i][j], 0, 0, 0);
        }
        __syncthreads();
    }

    // ---- Phases 2-3 per chunk (r7-verified). ------------------------------
    #pragma unroll
    for (int c = 0; c < 2; ++c) {
        const int nb = (row0 & 4095) + c * 64;

        // Phase 2a: +peb, normalize, s2/s6 reduce.
        #pragma unroll
        for (int i = 0; i < 4; ++i) {
            #pragma unroll
            for (int rg = 0; rg < 4; ++rg) {
                const int lrow = i * 16 + lq * 4 + rg;
                float s2 = 0.f, s6 = 0.f;
                #pragma unroll
                for (int j = 0; j < 4; ++j) {
                    const int col = wn + j * 16 + l15;
                    const float t = acc[c][i][j][rg] +
                        b2f(peb[(size_t)(nb + lrow) * 256 + col]);
                    const float xv = (fmaxf(t, 0.f) + 1e-6f) * sscr[col];
                    acc[c][i][j][rg] = xv;
                    const float x2 = xv * xv;
                    s2 += x2;
                    s6 += x2 * x2 * x2;
                }
                #pragma unroll
                for (int off = 1; off < 16; off <<= 1) {
                    s2 += __shfl_xor(s2, off);
                    s6 += __shfl_xor(s6, off);
                }
                if (l15 == 0) { red2[wv][lrow] = s2; red6[wv][lrow] = s6; }
            }
        }
        __syncthreads();
        if (tid < 64) {
            const float s2t = red2[0][tid] + red2[1][tid] + red2[2][tid] + red2[3][tid];
            const float s6t = red6[0][tid] + red6[1][tid] + red6[2][tid] + red6[3][tid];
            ratio_s[tid] = sqrtf(s2t / s6t);
        }
        __syncthreads();

        // Phase 2b: finalize k -> KsT[d][r] (swz); ksum partials.
        {
            float kscol[4] = {0.f, 0.f, 0.f, 0.f};
            #pragma unroll
            for (int i = 0; i < 4; ++i)
                #pragma unroll
                for (int rg = 0; rg < 4; ++rg) {
                    const int lrow = i * 16 + lq * 4 + rg;
                    const float rt = ratio_s[lrow];
                    #pragma unroll
                    for (int j = 0; j < 4; ++j) {
                        const float xv = acc[c][i][j][rg];
                        const float kf = xv * xv * xv * rt;
                        const int d = wn + j * 16 + l15;
                        KsT[d * 64 + swz(d, lrow)] = f2b(kf);
                        kscol[j] += kf;
                    }
                }
            #pragma unroll
            for (int j = 0; j < 4; ++j) {
                float kp = kscol[j];
                kp += __shfl_xor(kp, 16);
                kp += __shfl_xor(kp, 32);
                ksp[j] += kp;
            }
        }

        // Phase 3: two passes; pass p covers e in [128p, 128p+128).
        #pragma unroll
        for (int p = 0; p < 2; ++p) {
            {
                const u16* vg = v + (size_t)(row0 + c * 64 + lane) * 256 +
                                p * 128 + wv * 32;
                uint4 t0[4];
                #pragma unroll
                for (int j = 0; j < 4; ++j)
                    t0[j] = *reinterpret_cast<const uint4*>(vg + j * 8);
                #pragma unroll
                for (int j = 0; j < 4; ++j) {
                    const u16* pp = (const u16*)&t0[j];
                    #pragma unroll
                    for (int m = 0; m < 8; ++m) {
                        const int el = wv * 32 + j * 8 + m;   // 0..127
                        VsT[el * 64 + swz(el, lane)] = pp[m];
                    }
                }
            }
            __syncthreads();
            {
                const int h  = p * 4 + wv;
                const int cb = h * 32;        // d-base in KsT
                const int el = wv * 32;       // e-local base in VsT
                #pragma unroll
                for (int kk = 0; kk < 64; kk += 32) {
                    const int ko = kk + lq * 8;
                    const short8 a0 = *reinterpret_cast<const short8*>(
                        &KsT[(cb + l15) * 64 + swz(cb + l15, ko)]);
                    const short8 a1 = *reinterpret_cast<const short8*>(
                        &KsT[(cb + 16 + l15) * 64 + swz(cb + 16 + l15, ko)]);
                    const short8 b0 = *reinterpret_cast<const short8*>(
                        &VsT[(el + l15) * 64 + swz(el + l15, ko)]);
                    const short8 b1 = *reinterpret_cast<const short8*>(
                        &VsT[(el + 16 + l15) * 64 + swz(el + 16 + l15, ko)]);
                    cc[p][0] = __builtin_amdgcn_mfma_f32_16x16x32_bf16(a0, b0, cc[p][0], 0, 0, 0);
                    cc[p][1] = __builtin_amdgcn_mfma_f32_16x16x32_bf16(a0, b1, cc[p][1], 0, 0, 0);
                    cc[p][2] = __builtin_amdgcn_mfma_f32_16x16x32_bf16(a1, b0, cc[p][2], 0, 0, 0);
                    cc[p][3] = __builtin_amdgcn_mfma_f32_16x16x32_bf16(a1, b1, cc[p][3], 0, 0, 0);
                }
            }
            __syncthreads();
        }
    }

    // ---- Atomics once per block (2-slot hash). ----------------------------
    const int slot = blockIdx.x & 1;
    float* ksb = ksm + (size_t)(slot * 16 + b) * 256;
    #pragma unroll
    for (int j = 0; j < 4; ++j)
        if (lane < 16)
            atomicAdd(&ksb[wn + j * 16 + lane], ksp[j]);
    #pragma unroll
    for (int hh = 0; hh < 2; ++hh) {
        const int h = hh * 4 + wv;       // cc[hh] holds head 4*hh+wv
        float* base = kvsm + ((size_t)(slot * 16 + b) * 8 + h) * 1024;
        #pragma unroll
        for (int rg = 0; rg < 4; ++rg) {
            const int d0 = lq * 4 + rg;
            atomicAdd(&base[(size_t)d0 * 32 + l15],             cc[hh][0][rg]);
            atomicAdd(&base[(size_t)d0 * 32 + 16 + l15],        cc[hh][1][rg]);
            atomicAdd(&base[(size_t)(d0 + 16) * 32 + l15],      cc[hh][2][rg]);
            atomicAdd(&base[(size_t)(d0 + 16) * 32 + 16 + l15], cc[hh][3][rg]);
        }
    }
}

// ---------------------------------------------------------------------------
// attn (MFMA) IN-PLACE on qy: out[t][h*32+e] = (q[t]·kvT[h][e]) / (zd+eps).
// Sums the 2 kvsum/ksum slots.
// ---------------------------------------------------------------------------
__global__ __launch_bounds__(256, 2)
void attn_mfma_kernel(u16* __restrict__ qy, const float* __restrict__ kvsum,
                      const float* __restrict__ ksum)
{
    __shared__ u16 qs[64 * 256];         // swizzled rows (32 KB)
    __shared__ u16 kvT[8 * 32 * 40];     // [h][e][d], stride 40 (20 KB)
    __shared__ float km[8][32];
    __shared__ float zds[64][8];
    const int tid  = threadIdx.x;
    const int lane = tid & 63;
    const int wv   = tid >> 6;
    const int wvu  = __builtin_amdgcn_readfirstlane(wv);
    const int l15  = lane & 15;
    const int lq   = lane >> 4;
    const int b    = blockIdx.x >> 6;        // 64 blocks per batch
    const int n0   = (blockIdx.x & 63) * 64; // row base within batch
    const float inv_n = 1.0f / 4096.0f;

    // ---- Stage q rows via DMA (src pre-swizzled per row). -----------------
    {
        const int qr2 = lane >> 5;           // row within 2-row DMA group
        const int qc8 = (lane & 31) * 8;     // col (u16)
        const u16* qb = qy + (size_t)(b * 4096 + n0) * 256;
        #pragma unroll
        for (int it = 0; it < 8; ++it) {
            const int r = wvu * 16 + it * 2 + qr2;
            gl16(qb + (size_t)r * 256 + (qc8 ^ ((r & 7) << 3)),
                 &qs[(wvu * 16 + it * 2) * 256]);
        }
    }
    // ---- kvT + km staging (sum 2 slots). ----------------------------------
    {
        const int h = tid >> 5, e = tid & 31;
        const float* k0 = kvsum + (size_t)b * 8192 + h * 1024 + e;
        const float* k1 = kvsum + (size_t)(16 + b) * 8192 + h * 1024 + e;
        #pragma unroll
        for (int d = 0; d < 32; ++d)
            kvT[h * 1280 + e * 40 + d] = f2b((k0[d * 32] + k1[d * 32]) * inv_n);
        (&km[0][0])[tid] = (ksum[(size_t)b * 256 + tid] +
                            ksum[(size_t)(16 + b) * 256 + tid]) * inv_n;
    }
    __syncthreads();

    // ---- zd: once per (row, head); wave w handles heads 2w, 2w+1. ---------
    {
        const int zt = tid & 63;
        const int zh0 = (tid >> 6) * 2;
        #pragma unroll
        for (int hh = 0; hh < 2; ++hh) {
            const int h = zh0 + hh;
            float s = 0.f;
            #pragma unroll
            for (int d = 0; d < 32; ++d) {
                const int col = (h * 32 + d) ^ ((zt & 7) << 3);
                s = fmaf(b2f(qs[zt * 256 + col]), km[h][d], s);
            }
            zds[zt][h] = s;
        }
    }

    // ---- MFMA: wave rows [wvu*16, wvu*16+16), all 8 heads x 2 e-halves. ---
    f32x4 acc[8][2];
    #pragma unroll
    for (int h = 0; h < 8; ++h) {
        const int m = wvu * 16 + l15;
        const int col = (h * 32 + lq * 8) ^ ((m & 7) << 3);
        const short8 av = *reinterpret_cast<const short8*>(&qs[m * 256 + col]);
        const short8 b0 = *reinterpret_cast<const short8*>(
            &kvT[h * 1280 + l15 * 40 + lq * 8]);
        const short8 b1 = *reinterpret_cast<const short8*>(
            &kvT[h * 1280 + (16 + l15) * 40 + lq * 8]);
        const f32x4 z = {0.f, 0.f, 0.f, 0.f};
        acc[h][0] = __builtin_amdgcn_mfma_f32_16x16x32_bf16(av, b0, z, 0, 0, 0);
        acc[h][1] = __builtin_amdgcn_mfma_f32_16x16x32_bf16(av, b1, z, 0, 0, 0);
    }
    __syncthreads();

    // ---- Epilogue: divide by zd (broadcast read) and store. ---------------
    u16* qb = qy + (size_t)(b * 4096 + n0) * 256;
    #pragma unroll
    for (int h = 0; h < 8; ++h) {
        #pragma unroll
        for (int eh = 0; eh < 2; ++eh) {
            const int gcol = h * 32 + eh * 16 + l15;
            #pragma unroll
            for (int rg = 0; rg < 4; ++rg) {
                const int lr = wvu * 16 + lq * 4 + rg;
                const float z = 1.0f / (zds[lr][h] + 1e-6f);
                qb[(size_t)lr * 256 + gcol] = f2b(acc[h][eh][rg] * z);
            }
        }
    }
}

// ---------------------------------------------------------------------------
// Depthwise 5x5 conv: LDS-staged 12x12x256 halo tile, thread=channel,
// register sliding 5x12 window, 8x8 outputs/thread, += into y with bias.
// ---------------------------------------------------------------------------
__global__ __launch_bounds__(256, 2)
void conv_add_kernel(const u16* __restrict__ v, const void* __restrict__ w,
                     const void* __restrict__ bias, u16* __restrict__ y,
                     const int* __restrict__ flagp)
{
    const int f32 = *flagp;
    __shared__ u16 vt[144 * 256];   // [py*12+px][ch], 73728 B
    __shared__ float wl[800];
    __shared__ float bl[32];
    const int tid = threadIdx.x;
    for (int i = tid; i < 800; i += 256) wl[i] = ldv(w, i, f32);
    if (tid < 32) bl[tid] = ldv(bias, tid, f32);

    const int bb = blockIdx.x >> 6;
    const int ty = (blockIdx.x >> 3) & 7;
    const int tx = blockIdx.x & 7;
    const int y0 = ty * 8, x0 = tx * 8;
    const u16* vb = v + (size_t)bb * 4096 * 256;

    #pragma unroll
    for (int it = 0; it < 18; ++it) {
        const int idx = it * 256 + tid;       // 0..4607
        const int px  = idx >> 5;             // 0..143
        const int c8  = (idx & 31) * 8;
        const int py  = px / 12, pxx = px - py * 12;
        const int yy = y0 + py - 2, xx = x0 + pxx - 2;
        uint4 val = {0u, 0u, 0u, 0u};
        if (yy >= 0 && yy < 64 && xx >= 0 && xx < 64)
            val = *reinterpret_cast<const uint4*>(
                vb + (size_t)((yy << 6) + xx) * 256 + c8);
        *reinterpret_cast<uint4*>(&vt[px * 256 + c8]) = val;
    }
    __syncthreads();

    const int c  = tid;            // channel
    const int dc = c & 31;
    float wreg[25];
    #pragma unroll
    for (int i = 0; i < 25; ++i) wreg[i] = wl[dc * 25 + i];
    const float bv = bl[dc];

    float win[5][12];
    #pragma unroll
    for (int r = 0; r < 5; ++r)
        #pragma unroll
        for (int cc = 0; cc < 12; ++cc)
            win[r][cc] = b2f(vt[(r * 12 + cc) * 256 + c]);

    u16* yb = y + ((size_t)bb * 4096 + (size_t)y0 * 64 + x0) * 256 + c;
    #pragma unroll
    for (int oy = 0; oy < 8; ++oy) {
        if (oy) {
            #pragma unroll
            for (int r = 0; r < 4; ++r)
                #pragma unroll
                for (int cc = 0; cc < 12; ++cc) win[r][cc] = win[r + 1][cc];
            #pragma unroll
            for (int cc = 0; cc < 12; ++cc)
                win[4][cc] = b2f(vt[((oy + 4) * 12 + cc) * 256 + c]);
        }
        #pragma unroll
        for (int ox = 0; ox < 8; ++ox) {
            float s = 0.f;
            #pragma unroll
            for (int ky = 0; ky < 5; ++ky)
                #pragma unroll
                for (int kx = 0; kx < 5; ++kx)
                    s = fmaf(win[ky][ox + kx], wreg[ky * 5 + kx], s);
            u16* yp = yb + (size_t)(oy * 64 + ox) * 256;
            *yp = f2b(b2f(*yp) + s + bv);
        }
    }
}

// ---------------------------------------------------------------------------
extern "C" void kernel_launch(void* const* d_in, const int* in_sizes, int n_in,
                              void* d_out, int out_size, void* d_ws, size_t ws_size,
                              hipStream_t stream)
{
    (void)in_sizes; (void)n_in; (void)out_size;
    const void* x   = d_in[0];
    const void* Wq  = d_in[1];
    const void* Wkv = d_in[2];
    const void* Wp  = d_in[3];
    const void* bp  = d_in[4];
    const void* sp  = d_in[5];
    const void* pe  = d_in[6];
    const void* dw  = d_in[7];
    const void* db  = d_in[8];

    // ws layout:
    // [flag 64B][kvsm 1M (2 slots)][ksm 32K (2 slots)][WqT 128K][WkvT 256K]
    // [WpT 128K][peb 2M][qy 32M][xb 32M (only if ws large enough)]
    int*   flag = (int*)d_ws;
    float* kvsm = (float*)((char*)d_ws + 64);
    float* ksm  = kvsm + 262144;
    u16*   WqT  = (u16*)(ksm + 8192);
    u16*   WkvT = WqT + 65536;
    u16*   WpT  = WkvT + 131072;
    u16*   peb  = WpT + 65536;
    u16*   qy   = peb + 1048576;
    u16*   xb   = qy + (size_t)16777216;
    // v (bf16, 33.5 MB) parked at the START of d_out (dead before the final
    // GEMM overwrites d_out).
    u16*   v    = (u16*)d_out;

    const size_t need = (size_t)((char*)(xb + 16777216) - (char*)d_ws);
    const int big = (ws_size >= need) ? 1 : 0;

    hipMemsetAsync(kvsm, 0, (262144 + 8192) * sizeof(float), stream);
    detect_kernel<<<1, 64, 0, stream>>>(x, flag);
    if (big) xcvt_kernel<<<8192, 256, 0, stream>>>(x, xb, flag);
    prep_kernel<<<1280, 256, 0, stream>>>(pe, peb, Wq, WqT, Wkv, WkvT,
                                          Wp, WpT, flag);

    const void* Ax = big ? (const void*)xb : x;

    // q = focus(x @ Wq)
    hipLaunchKernelGGL((gemm256<3>), dim3(512), dim3(256), 0, stream,
                       Ax, (const u16*)nullptr, WqT, qy, sp, flag, big);
    // v = x @ Wkv[:, 256:]
    hipLaunchKernelGGL((gemm256<0>), dim3(512), dim3(256), 0, stream,
                       Ax, (const u16*)nullptr, WkvT + (size_t)256 * 256, v,
                       (const void*)nullptr, flag, big);
    // fused k path: gemm + pe + focus + kvsum/ksum (k never materialized)
    fusedk_kernel<<<512, 256, 0, stream>>>(Ax, WkvT, peb, v, sp, kvsm, ksm,
                                           flag, big);

    attn_mfma_kernel<<<1024, 256, 0, stream>>>(qy, kvsm, ksm);
    conv_add_kernel<<<1024, 256, 0, stream>>>(v, dw, db, qy, flag);
    hipLaunchKernelGGL((gemm256<2>), dim3(512), dim3(256), 0, stream,
                       (const void*)nullptr, qy, WpT, (u16*)d_out, bp, flag, 0);
}